// Round 2
// baseline (3762.274 us; speedup 1.0000x reference)
//
#include <hip/hip_runtime.h>
#include <hip/hip_bf16.h>

#define T_SEQ 512
#define BATCH 16
#define EMB 768
#define HEADS 32
#define HDIM 24
#define ROWS (T_SEQ * BATCH)  /* 8192 */
#define SCALING 0.20412414523193154f /* 24^-0.5 */

// ---------------------------------------------------------------------------
// Fused QKV projection: X[8192,768] @ W^T + b for W in {Wq,Wk,Wv}.
// Output layout [bh = b*32+h][t][dd] so attention reads are contiguous.
// Tile: 128x128, BK=16, 256 threads, 8x8 micro-tile (2x2 blocks of 4x4).
// LDS stored k-outer so ALL inner-loop reads are ds_read_b128.
// ---------------------------------------------------------------------------
__global__ __launch_bounds__(256)
void qkv_proj_kernel(const float* __restrict__ X,
                     const float* __restrict__ Wq, const float* __restrict__ Wk,
                     const float* __restrict__ Wv,
                     const float* __restrict__ bq, const float* __restrict__ bk,
                     const float* __restrict__ bv,
                     float* __restrict__ qo, float* __restrict__ ko,
                     float* __restrict__ vo)
{
    __shared__ __attribute__((aligned(16))) float Xs[16][132];
    __shared__ __attribute__((aligned(16))) float Ws[16][132];

    const int tid = threadIdx.x;
    const int r0 = blockIdx.x * 128;
    const int nb = blockIdx.y;            // 0..17 -> (q|k|v) x 6 col-blocks
    const int which = nb / 6;
    const int n0 = (nb % 6) * 128;
    const float* W    = (which == 0) ? Wq : (which == 1) ? Wk : Wv;
    const float* bias = (which == 0) ? bq : (which == 1) ? bk : bv;
    float* out        = (which == 0) ? qo : (which == 1) ? ko : vo;

    const int tx = tid & 15;              // n-dir
    const int ty = tid >> 4;              // m-dir

    const int srow = tid >> 2;            // 0..63
    const int skq  = (tid & 3) << 2;      // 0,4,8,12

    float acc[8][8] = {};

    for (int k0 = 0; k0 < EMB; k0 += 16) {
        const float4 x0 = *(const float4*)(X + (size_t)(r0 + srow) * EMB + k0 + skq);
        const float4 x1 = *(const float4*)(X + (size_t)(r0 + srow + 64) * EMB + k0 + skq);
        const float4 w0 = *(const float4*)(W + (size_t)(n0 + srow) * EMB + k0 + skq);
        const float4 w1 = *(const float4*)(W + (size_t)(n0 + srow + 64) * EMB + k0 + skq);
        __syncthreads();                  // previous iteration's reads complete
        Xs[skq + 0][srow] = x0.x; Xs[skq + 1][srow] = x0.y;
        Xs[skq + 2][srow] = x0.z; Xs[skq + 3][srow] = x0.w;
        Xs[skq + 0][srow + 64] = x1.x; Xs[skq + 1][srow + 64] = x1.y;
        Xs[skq + 2][srow + 64] = x1.z; Xs[skq + 3][srow + 64] = x1.w;
        Ws[skq + 0][srow] = w0.x; Ws[skq + 1][srow] = w0.y;
        Ws[skq + 2][srow] = w0.z; Ws[skq + 3][srow] = w0.w;
        Ws[skq + 0][srow + 64] = w1.x; Ws[skq + 1][srow + 64] = w1.y;
        Ws[skq + 2][srow + 64] = w1.z; Ws[skq + 3][srow + 64] = w1.w;
        __syncthreads();
#pragma unroll
        for (int kk = 0; kk < 16; ++kk) {
            const float4 a0 = *(const float4*)&Xs[kk][ty * 4];
            const float4 a1 = *(const float4*)&Xs[kk][ty * 4 + 64];
            const float4 b0 = *(const float4*)&Ws[kk][tx * 4];
            const float4 b1 = *(const float4*)&Ws[kk][tx * 4 + 64];
            const float a[8] = {a0.x, a0.y, a0.z, a0.w, a1.x, a1.y, a1.z, a1.w};
            const float b[8] = {b0.x, b0.y, b0.z, b0.w, b1.x, b1.y, b1.z, b1.w};
#pragma unroll
            for (int ii = 0; ii < 8; ++ii)
#pragma unroll
                for (int jj = 0; jj < 8; ++jj)
                    acc[ii][jj] += a[ii] * b[jj];
        }
    }

#pragma unroll
    for (int im = 0; im < 2; ++im)
#pragma unroll
    for (int ii = 0; ii < 4; ++ii) {
        const int rr = r0 + im * 64 + ty * 4 + ii;
        const int t = rr >> 4;
        const int b = rr & 15;
#pragma unroll
        for (int jn = 0; jn < 2; ++jn)
#pragma unroll
        for (int jj = 0; jj < 4; ++jj) {
            const int nn = n0 + jn * 64 + tx * 4 + jj;
            float c = acc[im * 4 + ii][jn * 4 + jj] + bias[nn];
            if (which == 0) c *= SCALING;
            const int h = nn / HDIM;
            const int dd = nn - h * HDIM;
            out[((size_t)((b * HEADS + h) * T_SEQ + t)) * HDIM + dd] = c;
        }
    }
}

// ---------------------------------------------------------------------------
// Attention, register-resident: one block per (bh, 16 query rows).
// Thread (i,g): query row i, score columns s = c*64 + g*4 + j  (c<8, j<4).
// Scores/probabilities live in p[32] registers (NO score LDS). Softmax
// reductions via width-16 __shfl_xor. PV accumulates a partial output row
// in acc[24] registers; single LDS round for the 16-lane cross-reduce.
// Bias streamed as coalesced float4. K/V rows = 6x dwordx4 (L1/L2 hits).
// XCD-bijective decode: each XCD owns 64 contiguous bh -> K/V fetched once.
// ---------------------------------------------------------------------------
__global__ __launch_bounds__(256)
void attn_kernel(const float* __restrict__ qb, const float* __restrict__ kb,
                 const float* __restrict__ vb, const float* __restrict__ bias,
                 float* __restrict__ attn)
{
    const int f = blockIdx.x;             // 0..16383
    const int xcd = f & 7;
    const int r = f >> 3;                 // 0..2047
    const int bh = xcd * 64 + (r >> 5);   // 64 bh per XCD, contiguous
    const int t0 = (r & 31) * 16;

    const int tid = threadIdx.x;
    const int i = tid >> 4;               // query row 0..15
    const int g = tid & 15;               // column group 0..15

    __shared__ float red[16 * 16 * 25];   // [i][g][25-slot], conflict-free
    __shared__ float rowinv[16];

    const float* Kb = kb + (size_t)bh * T_SEQ * HDIM;
    const float* Vb = vb + (size_t)bh * T_SEQ * HDIM;
    const float* Bb = bias + (size_t)bh * T_SEQ * T_SEQ + (size_t)(t0 + i) * T_SEQ;

    // Q row (already scaled by qkv kernel) into registers
    float q[HDIM];
    {
        const float4* qr = (const float4*)(qb + ((size_t)bh * T_SEQ + t0 + i) * HDIM);
#pragma unroll
        for (int u = 0; u < 6; ++u) {
            const float4 qv = qr[u];
            q[u * 4 + 0] = qv.x; q[u * 4 + 1] = qv.y;
            q[u * 4 + 2] = qv.z; q[u * 4 + 3] = qv.w;
        }
    }

    // scores -> p[32] (registers)
    float p[32];
#pragma unroll
    for (int c = 0; c < 8; ++c) {
        const float4 b4 = *(const float4*)(Bb + c * 64 + g * 4);
        const float bb[4] = {b4.x, b4.y, b4.z, b4.w};
#pragma unroll
        for (int j = 0; j < 4; ++j) {
            const int s = c * 64 + g * 4 + j;
            const float4* kr = (const float4*)(Kb + (size_t)s * HDIM);
            const float4 k0 = kr[0], k1 = kr[1], k2 = kr[2];
            const float4 k3 = kr[3], k4 = kr[4], k5 = kr[5];
            float d0 = q[0]  * k0.x + q[1]  * k0.y + q[2]  * k0.z + q[3]  * k0.w;
            float d1 = q[4]  * k1.x + q[5]  * k1.y + q[6]  * k1.z + q[7]  * k1.w;
            float d2 = q[8]  * k2.x + q[9]  * k2.y + q[10] * k2.z + q[11] * k2.w;
            float d3 = q[12] * k3.x + q[13] * k3.y + q[14] * k3.z + q[15] * k3.w;
            d0 += q[16] * k4.x + q[17] * k4.y + q[18] * k4.z + q[19] * k4.w;
            d1 += q[20] * k5.x + q[21] * k5.y + q[22] * k5.z + q[23] * k5.w;
            p[c * 4 + j] = (d0 + d1) + (d2 + d3) + bb[j];
        }
    }

    // row max across 32 local + 16 lanes
    float m = p[0];
#pragma unroll
    for (int k = 1; k < 32; ++k) m = fmaxf(m, p[k]);
#pragma unroll
    for (int st = 1; st < 16; st <<= 1) m = fmaxf(m, __shfl_xor(m, st, 16));

    // exp + row sum
    float l = 0.f;
#pragma unroll
    for (int k = 0; k < 32; ++k) { p[k] = __expf(p[k] - m); l += p[k]; }
#pragma unroll
    for (int st = 1; st < 16; st <<= 1) l += __shfl_xor(l, st, 16);
    if (g == 0) rowinv[i] = 1.f / l;

    // PV partial: acc[dd] = sum over this thread's s of P[s] * V[s][dd]
    float acc[HDIM] = {};
#pragma unroll
    for (int c = 0; c < 8; ++c) {
#pragma unroll
        for (int j = 0; j < 4; ++j) {
            const int s = c * 64 + g * 4 + j;
            const float4* vr = (const float4*)(Vb + (size_t)s * HDIM);
            const float pk = p[c * 4 + j];
#pragma unroll
            for (int u = 0; u < 6; ++u) {
                const float4 v4 = vr[u];
                acc[u * 4 + 0] += pk * v4.x;
                acc[u * 4 + 1] += pk * v4.y;
                acc[u * 4 + 2] += pk * v4.z;
                acc[u * 4 + 3] += pk * v4.w;
            }
        }
    }

    // cross-lane reduce via LDS (stride 25 floats: conflict-free scalar ops)
    float* myred = red + (i * 16 + g) * 25;
#pragma unroll
    for (int dd = 0; dd < HDIM; ++dd) myred[dd] = acc[dd];
    __syncthreads();

    const int b = bh >> 5;
    const int h = bh & 31;
    for (int pp = tid; pp < 16 * HDIM; pp += 256) {
        const int ii = pp / HDIM, dd = pp - ii * HDIM;
        float a = 0.f;
#pragma unroll
        for (int gg = 0; gg < 16; ++gg) a += red[(ii * 16 + gg) * 25 + dd];
        a *= rowinv[ii];
        const int t = t0 + ii;
        attn[((size_t)(t * BATCH + b)) * EMB + h * HDIM + dd] = a;
    }
}

// ---------------------------------------------------------------------------
// Output projection: attn[8192,768] @ Wo^T + bo -> out (same 128x128 tile)
// ---------------------------------------------------------------------------
__global__ __launch_bounds__(256)
void out_proj_kernel(const float* __restrict__ A, const float* __restrict__ Wo,
                     const float* __restrict__ bo, float* __restrict__ out)
{
    __shared__ __attribute__((aligned(16))) float Xs[16][132];
    __shared__ __attribute__((aligned(16))) float Ws[16][132];

    const int tid = threadIdx.x;
    const int r0 = blockIdx.x * 128;
    const int n0 = blockIdx.y * 128;

    const int tx = tid & 15;
    const int ty = tid >> 4;

    const int srow = tid >> 2;
    const int skq  = (tid & 3) << 2;

    float acc[8][8] = {};

    for (int k0 = 0; k0 < EMB; k0 += 16) {
        const float4 x0 = *(const float4*)(A + (size_t)(r0 + srow) * EMB + k0 + skq);
        const float4 x1 = *(const float4*)(A + (size_t)(r0 + srow + 64) * EMB + k0 + skq);
        const float4 w0 = *(const float4*)(Wo + (size_t)(n0 + srow) * EMB + k0 + skq);
        const float4 w1 = *(const float4*)(Wo + (size_t)(n0 + srow + 64) * EMB + k0 + skq);
        __syncthreads();
        Xs[skq + 0][srow] = x0.x; Xs[skq + 1][srow] = x0.y;
        Xs[skq + 2][srow] = x0.z; Xs[skq + 3][srow] = x0.w;
        Xs[skq + 0][srow + 64] = x1.x; Xs[skq + 1][srow + 64] = x1.y;
        Xs[skq + 2][srow + 64] = x1.z; Xs[skq + 3][srow + 64] = x1.w;
        Ws[skq + 0][srow] = w0.x; Ws[skq + 1][srow] = w0.y;
        Ws[skq + 2][srow] = w0.z; Ws[skq + 3][srow] = w0.w;
        Ws[skq + 0][srow + 64] = w1.x; Ws[skq + 1][srow + 64] = w1.y;
        Ws[skq + 2][srow + 64] = w1.z; Ws[skq + 3][srow + 64] = w1.w;
        __syncthreads();
#pragma unroll
        for (int kk = 0; kk < 16; ++kk) {
            const float4 a0 = *(const float4*)&Xs[kk][ty * 4];
            const float4 a1 = *(const float4*)&Xs[kk][ty * 4 + 64];
            const float4 b0 = *(const float4*)&Ws[kk][tx * 4];
            const float4 b1 = *(const float4*)&Ws[kk][tx * 4 + 64];
            const float a[8] = {a0.x, a0.y, a0.z, a0.w, a1.x, a1.y, a1.z, a1.w};
            const float b[8] = {b0.x, b0.y, b0.z, b0.w, b1.x, b1.y, b1.z, b1.w};
#pragma unroll
            for (int ii = 0; ii < 8; ++ii)
#pragma unroll
                for (int jj = 0; jj < 8; ++jj)
                    acc[ii][jj] += a[ii] * b[jj];
        }
    }

    const float4 bo0 = *(const float4*)(bo + n0 + tx * 4);
    const float4 bo1 = *(const float4*)(bo + n0 + 64 + tx * 4);
#pragma unroll
    for (int im = 0; im < 2; ++im)
#pragma unroll
    for (int ii = 0; ii < 4; ++ii) {
        const int rr = r0 + im * 64 + ty * 4 + ii;
        float4 c0, c1;
        c0.x = acc[im * 4 + ii][0] + bo0.x; c0.y = acc[im * 4 + ii][1] + bo0.y;
        c0.z = acc[im * 4 + ii][2] + bo0.z; c0.w = acc[im * 4 + ii][3] + bo0.w;
        c1.x = acc[im * 4 + ii][4] + bo1.x; c1.y = acc[im * 4 + ii][5] + bo1.y;
        c1.z = acc[im * 4 + ii][6] + bo1.z; c1.w = acc[im * 4 + ii][7] + bo1.w;
        *(float4*)(out + (size_t)rr * EMB + n0 + tx * 4) = c0;
        *(float4*)(out + (size_t)rr * EMB + n0 + 64 + tx * 4) = c1;
    }
}

extern "C" void kernel_launch(void* const* d_in, const int* in_sizes, int n_in,
                              void* d_out, int out_size, void* d_ws, size_t ws_size,
                              hipStream_t stream)
{
    const float* query = (const float*)d_in[0];   // [512,16,768]
    const float* abias = (const float*)d_in[1];   // [512,512,512]
    const float* Wq = (const float*)d_in[2];
    const float* bq = (const float*)d_in[3];
    const float* Wk = (const float*)d_in[4];
    const float* bk = (const float*)d_in[5];
    const float* Wv = (const float*)d_in[6];
    const float* bv = (const float*)d_in[7];
    const float* Wo = (const float*)d_in[8];
    const float* bo = (const float*)d_in[9];
    float* out = (float*)d_out;

    // workspace layout (floats): q | k | v | attn, each 512*512*24 or 8192*768
    float* ws = (float*)d_ws;
    const size_t QKV_ELEMS = (size_t)BATCH * HEADS * T_SEQ * HDIM; // 6291456
    float* qb = ws;
    float* kb = ws + QKV_ELEMS;
    float* vb = ws + 2 * QKV_ELEMS;
    float* ab = ws + 3 * QKV_ELEMS;                                // [8192,768]

    dim3 gA(ROWS / 128, 18);
    qkv_proj_kernel<<<gA, 256, 0, stream>>>(query, Wq, Wk, Wv, bq, bk, bv, qb, kb, vb);

    attn_kernel<<<dim3(BATCH * HEADS * (T_SEQ / 16)), 256, 0, stream>>>(qb, kb, vb, abias, ab);

    dim3 gC(ROWS / 128, EMB / 128);
    out_proj_kernel<<<gC, 256, 0, stream>>>(ab, Wo, bo, out);
}